// Round 5
// baseline (316.208 us; speedup 1.0000x reference)
//
#include <hip/hip_runtime.h>
#include <type_traits>

typedef short bf16x8 __attribute__((ext_vector_type(8)));
typedef float f32x4  __attribute__((ext_vector_type(4)));
typedef unsigned short u16;

#define MFMA(a,b,c) __builtin_amdgcn_mfma_f32_16x16x32_bf16((a),(b),(c),0,0,0)

__device__ __forceinline__ float bf2f(u16 u){ unsigned x=((unsigned)u)<<16; return __builtin_bit_cast(float,x); }
__device__ __forceinline__ u16 f2bf(float f){ unsigned x=__builtin_bit_cast(unsigned,f); x += 0x7fffu + ((x>>16)&1u); return (u16)(x>>16); }
__device__ __forceinline__ unsigned pkbf(float a, float b){
  unsigned ua = __builtin_bit_cast(unsigned, a), ub = __builtin_bit_cast(unsigned, b);
  ua += 0x7fffu + ((ua>>16)&1u);
  ub += 0x7fffu + ((ub>>16)&1u);
  return __builtin_amdgcn_perm(ub, ua, 0x07060302u);
}
__device__ __forceinline__ void async_cp16(const u16* g, u16* l){
  __builtin_amdgcn_global_load_lds((const __attribute__((address_space(1))) void*)g,
                                   (__attribute__((address_space(3))) void*)l, 16, 0, 0);
}

// ---------------- fp32 -> bf16 convert ----------------
__global__ __launch_bounds__(256) void cvt_f32_bf16(const float* __restrict__ in, u16* __restrict__ out, int n){
  int i = (blockIdx.x*256 + threadIdx.x)*4;
  if (i >= n) return;
  float4 v = *(const float4*)(in + i);
  ushort4 o;
  o.x = f2bf(v.x); o.y = f2bf(v.y); o.z = f2bf(v.z); o.w = f2bf(v.w);
  *(ushort4*)(out + i) = o;
}

// ---------------- fp32 [R][C] -> bf16 [C][R] transpose ----------------
__global__ __launch_bounds__(256) void transpose_f32_bf16(const float* __restrict__ in, u16* __restrict__ out, int R, int C){
  __shared__ u16 tile[32][33];
  int bc = blockIdx.x*32, br = blockIdx.y*32;
  int tx = threadIdx.x & 31, ty = threadIdx.x >> 5;
  #pragma unroll
  for (int i=ty;i<32;i+=8) tile[i][tx] = f2bf(in[(size_t)(br+i)*C + bc + tx]);
  __syncthreads();
  #pragma unroll
  for (int i=ty;i<32;i+=8) out[(size_t)(bc+i)*R + br + tx] = tile[tx][i];
}

// ---------------- per-head bf16 transpose: [16][4096][64] -> [16][64][4096] ----------------
__global__ __launch_bounds__(256) void vtrans_bf16(const u16* __restrict__ in, u16* __restrict__ out){
  __shared__ u16 tile[32][33];
  const int h = blockIdx.z;
  const u16* ip = in + (size_t)h*4096*64;
  u16* op = out + (size_t)h*64*4096;
  int bt = blockIdx.x*32, bd = blockIdx.y*32;
  int tx = threadIdx.x & 31, ty = threadIdx.x >> 5;
  #pragma unroll
  for (int i=ty;i<32;i+=8) tile[i][tx] = ip[(size_t)(bt+i)*64 + bd + tx];
  __syncthreads();
  #pragma unroll
  for (int i=ty;i<32;i+=8) op[(size_t)(bd+i)*4096 + bt + tx] = tile[tx][i];
}

// ---------------- GEMM: C[M][N] = A[M][K] @ Bt[N][K]^T + bias ----------------
// 128xBN tile, BK=32, async swizzled staging (XOR chunk^row&3 kills the 8-way read conflict).
template<int BN, typename OutT>
__global__ __launch_bounds__(256) void gemm_bt_bias(
    const u16* __restrict__ A, const u16* __restrict__ Bt,
    const float* __restrict__ bias, OutT* __restrict__ C,
    int M, int N, int K)
{
  __shared__ __align__(16) u16 As[128*32];
  __shared__ __align__(16) u16 Bs[BN*32];
  const int m0 = blockIdx.y*128, n0 = blockIdx.x*BN;
  const int tid = threadIdx.x;
  const int wave = tid>>6, lane = tid&63;
  const int wr = (wave>>1)*64, wc = (wave&1)*(BN/2);
  const int ml = lane&15, quad = lane>>4;
  const int lrow = lane>>2;
  const int scol = ((lane&3) ^ (lrow&3))*8;      // swizzled global column for staging
  const int rsw  = (quad ^ (ml&3))*8;            // swizzled read column
  const u16* gA0 = A + (size_t)(m0 + wave*32      + lrow)*K + scol;
  const u16* gA1 = A + (size_t)(m0 + wave*32 + 16 + lrow)*K + scol;
  u16* lA0 = &As[wave*1024];
  u16* lA1 = &As[wave*1024 + 512];
  constexpr int BI = BN/64;     // B staging issues per wave
  const u16* gB[BI]; u16* lB[BI];
  #pragma unroll
  for (int t=0;t<BI;t++){
    gB[t] = Bt + (size_t)(n0 + (wave*BI+t)*16 + lrow)*K + scol;
    lB[t] = &Bs[(wave*BI+t)*512];
  }
  constexpr int NJ = BN/32;
  f32x4 acc[4][NJ] = {};
  for (int k0=0; k0<K; k0+=32) {
    async_cp16(gA0 + k0, lA0);
    async_cp16(gA1 + k0, lA1);
    #pragma unroll
    for (int t=0;t<BI;t++) async_cp16(gB[t] + k0, lB[t]);
    __syncthreads();
    bf16x8 af[4], bfr[NJ];
    #pragma unroll
    for (int i=0;i<4;i++)  af[i]  = *(const bf16x8*)&As[(wr+i*16+ml)*32 + rsw];
    #pragma unroll
    for (int j=0;j<NJ;j++) bfr[j] = *(const bf16x8*)&Bs[(wc+j*16+ml)*32 + rsw];
    #pragma unroll
    for (int i=0;i<4;i++)
      #pragma unroll
      for (int j=0;j<NJ;j++)
        acc[i][j] = MFMA(af[i], bfr[j], acc[i][j]);
    __syncthreads();
  }
  #pragma unroll
  for (int j=0;j<NJ;j++){
    int col = n0 + wc + j*16 + ml;
    float bv = bias[col];
    #pragma unroll
    for (int i=0;i<4;i++){
      int row0 = m0 + wr + i*16 + quad*4;
      #pragma unroll
      for (int r=0;r<4;r++){
        float val = acc[i][j][r] + bv;
        if constexpr (std::is_same_v<OutT, float>)
          C[(size_t)(row0+r)*N + col] = val;
        else
          C[(size_t)(row0+r)*N + col] = f2bf(val);
      }
    }
  }
}

// ---------------- RoPE + split qkv -> Q (pre-scaled 0.125*log2e), K, V row-major ----------------
__global__ __launch_bounds__(256) void rope_split(
    const u16* __restrict__ QKV, const float* __restrict__ cosb, const float* __restrict__ sinb,
    u16* __restrict__ Qo, u16* __restrict__ Ko, u16* __restrict__ Vo)
{
  const int t = blockIdx.x;
  const int d = threadIdx.x & 63;
  const int h0 = threadIdx.x >> 6;
  const float cv = cosb[t*64+d];
  const float sv = sinb[t*64+d];
  const int dp = (d<32) ? d+32 : d-32;
  const float sgn = (d<32) ? -1.f : 1.f;
  #pragma unroll
  for (int h=h0; h<16; h+=4) {
    const u16* base = QKV + (size_t)t*3072 + h*64;
    float q  = bf2f(base[d]);
    float k  = bf2f(base[1024+d]);
    float v  = bf2f(base[2048+d]);
    float qp = bf2f(base[dp]);
    float kp = bf2f(base[1024+dp]);
    float qr = q*cv + sgn*qp*sv;
    float kr = k*cv + sgn*kp*sv;
    Qo[((size_t)h*4096 + t)*64 + d] = f2bf(qr*(0.125f*1.44269504f));
    Ko[((size_t)h*4096 + t)*64 + d] = f2bf(kr);
    Vo[((size_t)h*4096 + t)*64 + d] = f2bf(v);
  }
}

// ---------------- flash attention, K-split x2, async swizzled staging ----------------
// grid (32 qt, 16 h, 2 ks). Block: 4 waves x 32 q = 128 q; 2048 keys per block, BK=64.
// No-rescale softmax (Q pre-scaled 0.125*log2e): partials over key-splits are exactly additive.
// Outputs: unnormalized O partial (bf16) + per-row sums.
__global__ __launch_bounds__(256) void flash_attn(
    const u16* __restrict__ Q, const u16* __restrict__ Kg, const u16* __restrict__ VT,
    u16* __restrict__ Opart, float* __restrict__ Lpart)
{
  constexpr int SEQ=4096, HALF=2048, LPP=72;
  __shared__ __align__(16) u16 Ks[64*64];     // [64 keys][64 d], chunk-swizzled
  __shared__ __align__(16) u16 Vs[64*64];     // [64 d][64 keys], chunk-swizzled
  __shared__ __align__(16) u16 Ps[4][32*LPP]; // per-wave [32 q][64+8 keys]
  const int qt=blockIdx.x, h=blockIdx.y, ks=blockIdx.z;
  const int tid=threadIdx.x, wave=tid>>6, lane=tid&63;
  const int ml=lane&15, quad=lane>>4;
  const int qbase = qt*128 + wave*32;
  bf16x8 qf[2][2];
  #pragma unroll
  for (int qi=0; qi<2; qi++){
    const u16* qp = Q + ((size_t)h*SEQ + qbase + qi*16 + ml)*64;
    qf[qi][0] = *(const bf16x8*)(qp + quad*8);
    qf[qi][1] = *(const bf16x8*)(qp + 32 + quad*8);
  }
  f32x4 o[2][4] = {};
  float lsum[2] = {0.f,0.f};
  // staging lane geometry: each global_load_lds issue = 8 rows x 64 u16; lane l -> row l>>3, chunk l&7.
  // LDS slot (row,c) holds global chunk c^(row&7)  =>  lane fetches global chunk (l&7)^((l>>3)&7).
  const int lrow8 = lane>>3, lchk = lane&7;
  const int swzg = ((lchk ^ (lrow8&7))*8);
  const u16* kgl = Kg + (size_t)h*SEQ*64 + (size_t)(ks*HALF + wave*16 + lrow8)*64 + swzg;
  const u16* vgl = VT + (size_t)h*64*SEQ + (size_t)(wave*16 + lrow8)*SEQ + ks*HALF + swzg;
  u16* kl0 = &Ks[(wave*16  )*64];
  u16* kl1 = &Ks[(wave*16+8)*64];
  u16* vl0 = &Vs[(wave*16  )*64];
  u16* vl1 = &Vs[(wave*16+8)*64];
  const int swz0 = ((quad  ) ^ (ml&7))*8;   // read-side swizzle, chunks quad / quad+4
  const int swz1 = ((quad+4) ^ (ml&7))*8;
  u16* pw = Ps[wave];

  for (int k0=0;k0<HALF;k0+=64) {
    async_cp16(kgl + (size_t)k0*64,       kl0);
    async_cp16(kgl + (size_t)k0*64 + 512, kl1);
    async_cp16(vgl + k0,                  vl0);
    async_cp16(vgl + 8*SEQ + k0,          vl1);
    __syncthreads();
    bf16x8 kf[4][2], vf[4][2];
    #pragma unroll
    for (int b=0;b<4;b++){
      kf[b][0] = *(const bf16x8*)&Ks[(b*16+ml)*64 + swz0];
      kf[b][1] = *(const bf16x8*)&Ks[(b*16+ml)*64 + swz1];
      vf[b][0] = *(const bf16x8*)&Vs[(b*16+ml)*64 + swz0];
      vf[b][1] = *(const bf16x8*)&Vs[(b*16+ml)*64 + swz1];
    }
    #pragma unroll
    for (int qi=0; qi<2; qi++){
      // S^T[key][q]: lane (ml=q, quad), reg r -> key = kb*16 + quad*4 + r
      f32x4 s[4];
      #pragma unroll
      for (int kb=0;kb<4;kb++){
        f32x4 z = {0,0,0,0};
        z = MFMA(kf[kb][0], qf[qi][0], z);
        s[kb] = MFMA(kf[kb][1], qf[qi][1], z);
      }
      #pragma unroll
      for (int kb=0;kb<4;kb++){
        float p0=exp2f(s[kb][0]), p1=exp2f(s[kb][1]), p2=exp2f(s[kb][2]), p3=exp2f(s[kb][3]);
        lsum[qi] += (p0+p1)+(p2+p3);
        uint2 pk; pk.x = pkbf(p0,p1); pk.y = pkbf(p2,p3);
        *(uint2*)&pw[(qi*16+ml)*LPP + kb*16 + quad*4] = pk;
      }
      bf16x8 pf0 = *(const bf16x8*)&pw[(qi*16+ml)*LPP + quad*8];
      bf16x8 pf1 = *(const bf16x8*)&pw[(qi*16+ml)*LPP + 32 + quad*8];
      #pragma unroll
      for (int db=0;db<4;db++){
        o[qi][db] = MFMA(pf0, vf[db][0], o[qi][db]);
        o[qi][db] = MFMA(pf1, vf[db][1], o[qi][db]);
      }
    }
    __syncthreads();
  }
  u16* op = Opart + (size_t)ks*4096*1024;
  #pragma unroll
  for (int qi=0;qi<2;qi++)
    #pragma unroll
    for (int r=0;r<4;r++){
      int row = qbase + qi*16 + quad*4 + r;
      size_t ob = (size_t)row*1024 + h*64;
      #pragma unroll
      for (int db=0;db<4;db++)
        op[ob + db*16 + ml] = f2bf(o[qi][db][r]);
    }
  lsum[0] += __shfl_xor(lsum[0],16,64); lsum[0] += __shfl_xor(lsum[0],32,64);
  lsum[1] += __shfl_xor(lsum[1],16,64); lsum[1] += __shfl_xor(lsum[1],32,64);
  if (quad==0){
    float* lp = Lpart + (size_t)ks*16*4096 + (size_t)h*4096 + qbase;
    lp[ml]    = lsum[0];
    lp[16+ml] = lsum[1];
  }
}

// ---------------- combine the two K-split partials, normalize, emit bf16 AO ----------------
__global__ __launch_bounds__(256) void combine_softmax(
    const u16* __restrict__ O0, const u16* __restrict__ O1,
    const float* __restrict__ L0, const float* __restrict__ L1,
    u16* __restrict__ AO)
{
  int i = (blockIdx.x*256 + threadIdx.x)*4;
  int row = i >> 10, col = i & 1023, h = col >> 6;
  float inv = 1.f/(L0[h*4096 + row] + L1[h*4096 + row]);
  ushort4 a = *(const ushort4*)(O0+i);
  ushort4 b = *(const ushort4*)(O1+i);
  ushort4 o;
  o.x = f2bf((bf2f(a.x)+bf2f(b.x))*inv);
  o.y = f2bf((bf2f(a.y)+bf2f(b.y))*inv);
  o.z = f2bf((bf2f(a.z)+bf2f(b.z))*inv);
  o.w = f2bf((bf2f(a.w)+bf2f(b.w))*inv);
  *(ushort4*)(AO+i) = o;
}

extern "C" void kernel_launch(void* const* d_in, const int* in_sizes, int n_in,
                              void* d_out, int out_size, void* d_ws, size_t ws_size,
                              hipStream_t stream)
{
  (void)in_sizes; (void)n_in; (void)out_size; (void)ws_size;
  const float* H     = (const float*)d_in[0];
  // d_in[1] = cu_seqlens (unused by reference)
  const float* cosb  = (const float*)d_in[2];
  const float* sinb  = (const float*)d_in[3];
  const float* Wqkv  = (const float*)d_in[4];
  const float* bqkv  = (const float*)d_in[5];
  const float* Wproj = (const float*)d_in[6];
  const float* bproj = (const float*)d_in[7];
  float* out = (float*)d_out;
  char* ws = (char*)d_ws;
  // 64 MiB total, aliasing dead regions:
  u16*   WqkvT  = (u16*)(ws + 0);          // [3072][1024] bf16, 6 MB; dead after QKV gemm
  float* Lpart  = (float*)(ws + 0);        // [2][16][4096] f32, 0.5 MB (reuses WqkvT)
  u16*   WprojT = (u16*)(ws + 6291456);    // [1024][1024] bf16, 2 MB
  u16*   Hb     = (u16*)(ws + 8388608);    // [4096][1024] bf16, 8 MB; dead after QKV gemm
  u16*   AO     = (u16*)(ws + 8388608);    // combine output (reuses Hb)
  u16*   QKVr   = (u16*)(ws + 16777216);   // [4096][3072] bf16, 24 MB; dead after rope
  u16*   VTb    = (u16*)(ws + 16777216);   // [16][64][4096], 8 MB (front of QKVr)
  u16*   Opart  = (u16*)(ws + 25165824);   // [2][4096][1024] bf16, 16 MB (rest of QKVr)
  u16*   Qb     = (u16*)(ws + 41943040);   // [16][4096][64], 8 MB
  u16*   Kb     = (u16*)(ws + 50331648);   // [16][4096][64], 8 MB
  u16*   Vb     = (u16*)(ws + 58720256);   // [16][4096][64], 8 MB

  hipLaunchKernelGGL(cvt_f32_bf16, dim3(4096), dim3(256), 0, stream, H, Hb, 4096*1024);
  hipLaunchKernelGGL(transpose_f32_bf16, dim3(96,32), dim3(256), 0, stream, Wqkv, WqkvT, 1024, 3072);
  hipLaunchKernelGGL(transpose_f32_bf16, dim3(32,32), dim3(256), 0, stream, Wproj, WprojT, 1024, 1024);
  hipLaunchKernelGGL((gemm_bt_bias<128,u16>), dim3(24,32), dim3(256), 0, stream, Hb, WqkvT, bqkv, QKVr, 4096, 3072, 1024);
  hipLaunchKernelGGL(rope_split, dim3(4096), dim3(256), 0, stream, QKVr, cosb, sinb, Qb, Kb, Vb);
  hipLaunchKernelGGL(vtrans_bf16, dim3(128,2,16), dim3(256), 0, stream, Vb, VTb);
  hipLaunchKernelGGL(flash_attn, dim3(32,16,2), dim3(256), 0, stream, Qb, Kb, VTb, Opart, Lpart);
  hipLaunchKernelGGL(combine_softmax, dim3(4096), dim3(256), 0, stream,
                     Opart, Opart + (size_t)4096*1024, Lpart, Lpart + 16*4096, AO);
  hipLaunchKernelGGL((gemm_bt_bias<64,float>), dim3(16,32), dim3(256), 0, stream, AO, WprojT, bproj, out, 4096, 1024, 1024);
}

// Round 6
// 279.406 us; speedup vs baseline: 1.1317x; 1.1317x over previous
//
#include <hip/hip_runtime.h>
#include <type_traits>

typedef short bf16x8 __attribute__((ext_vector_type(8)));
typedef float f32x4  __attribute__((ext_vector_type(4)));
typedef unsigned short u16;

#define MFMA(a,b,c) __builtin_amdgcn_mfma_f32_16x16x32_bf16((a),(b),(c),0,0,0)

__device__ __forceinline__ float bf2f(u16 u){ unsigned x=((unsigned)u)<<16; return __builtin_bit_cast(float,x); }
__device__ __forceinline__ u16 f2bf(float f){ unsigned x=__builtin_bit_cast(unsigned,f); x += 0x7fffu + ((x>>16)&1u); return (u16)(x>>16); }
__device__ __forceinline__ unsigned pkbf(float a, float b){
  unsigned ua = __builtin_bit_cast(unsigned, a), ub = __builtin_bit_cast(unsigned, b);
  ua += 0x7fffu + ((ua>>16)&1u);
  ub += 0x7fffu + ((ub>>16)&1u);
  return __builtin_amdgcn_perm(ub, ua, 0x07060302u);
}
__device__ __forceinline__ void async_cp16(const u16* g, u16* l){
  __builtin_amdgcn_global_load_lds((const __attribute__((address_space(1))) void*)g,
                                   (__attribute__((address_space(3))) void*)l, 16, 0, 0);
}

// ---------------- fp32 -> bf16 convert ----------------
__global__ __launch_bounds__(256) void cvt_f32_bf16(const float* __restrict__ in, u16* __restrict__ out, int n){
  int i = (blockIdx.x*256 + threadIdx.x)*4;
  if (i >= n) return;
  float4 v = *(const float4*)(in + i);
  ushort4 o;
  o.x = f2bf(v.x); o.y = f2bf(v.y); o.z = f2bf(v.z); o.w = f2bf(v.w);
  *(ushort4*)(out + i) = o;
}

// ---------------- fp32 [R][C] -> bf16 [C][R] transpose ----------------
__global__ __launch_bounds__(256) void transpose_f32_bf16(const float* __restrict__ in, u16* __restrict__ out, int R, int C){
  __shared__ u16 tile[32][33];
  int bc = blockIdx.x*32, br = blockIdx.y*32;
  int tx = threadIdx.x & 31, ty = threadIdx.x >> 5;
  #pragma unroll
  for (int i=ty;i<32;i+=8) tile[i][tx] = f2bf(in[(size_t)(br+i)*C + bc + tx]);
  __syncthreads();
  #pragma unroll
  for (int i=ty;i<32;i+=8) out[(size_t)(bc+i)*R + br + tx] = tile[tx][i];
}

// ---------------- per-head bf16 transpose WITH key-permutation ----------------
// in [16][4096][64] -> out [16][64][4096], columns permuted within each 32-key group:
// physical col quad*8 + b*4 + r  holds logical key b*16 + quad*4 + r.
// This makes the S^T MFMA output fragment directly usable as PV's B-operand (no LDS P round-trip).
__global__ __launch_bounds__(256) void vtrans_perm_bf16(const u16* __restrict__ in, u16* __restrict__ out){
  __shared__ u16 tile[32][33];
  const int h = blockIdx.z;
  const u16* ip = in + (size_t)h*4096*64;
  u16* op = out + (size_t)h*64*4096;
  int bt = blockIdx.x*32, bd = blockIdx.y*32;
  int tx = threadIdx.x & 31, ty = threadIdx.x >> 5;
  #pragma unroll
  for (int i=ty;i<32;i+=8) tile[i][tx] = ip[(size_t)(bt+i)*64 + bd + tx];
  __syncthreads();
  // physical position tx <- logical t  finv(tx) = ((tx>>2)&1)*16 + (tx>>3)*4 + (tx&3)
  const int tlog = ((tx>>2)&1)*16 + (tx>>3)*4 + (tx&3);
  #pragma unroll
  for (int i=ty;i<32;i+=8) op[(size_t)(bd+i)*4096 + bt + tx] = tile[tlog][i];
}

// ---------------- GEMM: C[M][N] = A[M][K] @ Bt[N][K]^T + bias ----------------
template<int BN, typename OutT>
__global__ __launch_bounds__(256) void gemm_bt_bias(
    const u16* __restrict__ A, const u16* __restrict__ Bt,
    const float* __restrict__ bias, OutT* __restrict__ C,
    int M, int N, int K)
{
  __shared__ __align__(16) u16 As[128*32];
  __shared__ __align__(16) u16 Bs[BN*32];
  const int m0 = blockIdx.y*128, n0 = blockIdx.x*BN;
  const int tid = threadIdx.x;
  const int wave = tid>>6, lane = tid&63;
  const int wr = (wave>>1)*64, wc = (wave&1)*(BN/2);
  const int ml = lane&15, quad = lane>>4;
  const int lrow = lane>>2;
  const int scol = ((lane&3) ^ (lrow&3))*8;
  const int rsw  = (quad ^ (ml&3))*8;
  const u16* gA0 = A + (size_t)(m0 + wave*32      + lrow)*K + scol;
  const u16* gA1 = A + (size_t)(m0 + wave*32 + 16 + lrow)*K + scol;
  u16* lA0 = &As[wave*1024];
  u16* lA1 = &As[wave*1024 + 512];
  constexpr int BI = BN/64;
  const u16* gB[BI]; u16* lB[BI];
  #pragma unroll
  for (int t=0;t<BI;t++){
    gB[t] = Bt + (size_t)(n0 + (wave*BI+t)*16 + lrow)*K + scol;
    lB[t] = &Bs[(wave*BI+t)*512];
  }
  constexpr int NJ = BN/32;
  f32x4 acc[4][NJ] = {};
  for (int k0=0; k0<K; k0+=32) {
    async_cp16(gA0 + k0, lA0);
    async_cp16(gA1 + k0, lA1);
    #pragma unroll
    for (int t=0;t<BI;t++) async_cp16(gB[t] + k0, lB[t]);
    __syncthreads();
    bf16x8 af[4], bfr[NJ];
    #pragma unroll
    for (int i=0;i<4;i++)  af[i]  = *(const bf16x8*)&As[(wr+i*16+ml)*32 + rsw];
    #pragma unroll
    for (int j=0;j<NJ;j++) bfr[j] = *(const bf16x8*)&Bs[(wc+j*16+ml)*32 + rsw];
    #pragma unroll
    for (int i=0;i<4;i++)
      #pragma unroll
      for (int j=0;j<NJ;j++)
        acc[i][j] = MFMA(af[i], bfr[j], acc[i][j]);
    __syncthreads();
  }
  #pragma unroll
  for (int j=0;j<NJ;j++){
    int col = n0 + wc + j*16 + ml;
    float bv = bias[col];
    #pragma unroll
    for (int i=0;i<4;i++){
      int row0 = m0 + wr + i*16 + quad*4;
      #pragma unroll
      for (int r=0;r<4;r++){
        float val = acc[i][j][r] + bv;
        if constexpr (std::is_same_v<OutT, float>)
          C[(size_t)(row0+r)*N + col] = val;
        else
          C[(size_t)(row0+r)*N + col] = f2bf(val);
      }
    }
  }
}

// ---------------- RoPE + split qkv -> Q (pre-scaled 0.125*log2e), K, V row-major ----------------
__global__ __launch_bounds__(256) void rope_split(
    const u16* __restrict__ QKV, const float* __restrict__ cosb, const float* __restrict__ sinb,
    u16* __restrict__ Qo, u16* __restrict__ Ko, u16* __restrict__ Vo)
{
  const int t = blockIdx.x;
  const int d = threadIdx.x & 63;
  const int h0 = threadIdx.x >> 6;
  const float cv = cosb[t*64+d];
  const float sv = sinb[t*64+d];
  const int dp = (d<32) ? d+32 : d-32;
  const float sgn = (d<32) ? -1.f : 1.f;
  #pragma unroll
  for (int h=h0; h<16; h+=4) {
    const u16* base = QKV + (size_t)t*3072 + h*64;
    float q  = bf2f(base[d]);
    float k  = bf2f(base[1024+d]);
    float v  = bf2f(base[2048+d]);
    float qp = bf2f(base[dp]);
    float kp = bf2f(base[1024+dp]);
    float qr = q*cv + sgn*qp*sv;
    float kr = k*cv + sgn*kp*sv;
    Qo[((size_t)h*4096 + t)*64 + d] = f2bf(qr*(0.125f*1.44269504f));
    Ko[((size_t)h*4096 + t)*64 + d] = f2bf(kr);
    Vo[((size_t)h*4096 + t)*64 + d] = f2bf(v);
  }
}

// ---------------- flash attention: in-register P, no P LDS round-trip ----------------
// grid (32 qt, 16 h, 2 ks); 4 waves x 32 q; BK=64; K-split x2 partials (additive, no-rescale softmax).
// S^T = MFMA(A=K,B=Q) -> lane(ml=q,quad) reg r: key = kb*16+quad*4+r.
// V^T stored with permuted columns so P frags feed PV MFMA (B-operand) directly from registers.
// Row sums via ones-fragment MFMA (replicated into every lane).
__global__ __launch_bounds__(256,4) void flash_attn(
    const u16* __restrict__ Q, const u16* __restrict__ Kg, const u16* __restrict__ VT,
    u16* __restrict__ Opart, float* __restrict__ Lpart)
{
  constexpr int SEQ=4096, HALF=2048;
  __shared__ __align__(16) u16 Ks[64*64];   // [64 keys][64 d], chunk-swizzled (c^=row&7)
  __shared__ __align__(16) u16 Vs[64*64];   // [64 d][64 keys(permuted)], chunk-swizzled
  const int qt=blockIdx.x, h=blockIdx.y, ks=blockIdx.z;
  const int tid=threadIdx.x, wave=tid>>6, lane=tid&63;
  const int ml=lane&15, quad=lane>>4;
  const int qbase = qt*128 + wave*32;
  bf16x8 qf[2][2];
  #pragma unroll
  for (int qi=0; qi<2; qi++){
    const u16* qp = Q + ((size_t)h*SEQ + qbase + qi*16 + ml)*64;
    qf[qi][0] = *(const bf16x8*)(qp + quad*8);
    qf[qi][1] = *(const bf16x8*)(qp + 32 + quad*8);
  }
  const bf16x8 ones = {0x3F80,0x3F80,0x3F80,0x3F80,0x3F80,0x3F80,0x3F80,0x3F80};
  f32x4 o[2][4] = {};
  f32x4 accsum[2] = {};
  // staging: each async_cp16 = 8 rows x 64 u16; lane l -> row l>>3, phys chunk l&7.
  // stored chunk c' = c ^ (row&7)  =>  lane fetches global chunk (l&7)^(l>>3).
  const int lrow8 = lane>>3, lchk = lane&7;
  const int swzg = (lchk ^ lrow8)*8;
  const u16* kgl = Kg + (size_t)h*SEQ*64 + (size_t)(ks*HALF + wave*16 + lrow8)*64 + swzg;
  const u16* vgl = VT + (size_t)h*64*SEQ + (size_t)(wave*16 + lrow8)*SEQ + ks*HALF + swzg;
  u16* kl0 = &Ks[(wave*16  )*64];
  u16* kl1 = &Ks[(wave*16+8)*64];
  u16* vl0 = &Vs[(wave*16  )*64];
  u16* vl1 = &Vs[(wave*16+8)*64];
  const int swzA = (quad     ^ (ml&7))*8;   // logical chunk quad   (d or keys 0..31 half)
  const int swzB = ((quad^4) ^ (ml&7))*8;   // logical chunk quad+4

  for (int k0=0;k0<HALF;k0+=64) {
    async_cp16(kgl + (size_t)k0*64,       kl0);
    async_cp16(kgl + (size_t)k0*64 + 512, kl1);
    async_cp16(vgl + k0,                  vl0);
    async_cp16(vgl + 8*SEQ + k0,          vl1);
    __syncthreads();
    // hoist V fragments (A-operand rows d=db*16+ml, key-pair p chunks p*4+quad)
    bf16x8 vf[4][2];
    #pragma unroll
    for (int db=0;db<4;db++){
      vf[db][0] = *(const bf16x8*)&Vs[(db*16+ml)*64 + (( (quad  ) ^ (ml&7))*8)];
      vf[db][1] = *(const bf16x8*)&Vs[(db*16+ml)*64 + (( (quad|4) ^ (ml&7))*8)];
    }
    #pragma unroll
    for (int qi=0; qi<2; qi++){
      f32x4 s[4];
      #pragma unroll
      for (int kb=0;kb<4;kb++){
        bf16x8 kf0 = *(const bf16x8*)&Ks[(kb*16+ml)*64 + swzA];
        bf16x8 kf1 = *(const bf16x8*)&Ks[(kb*16+ml)*64 + swzB];
        f32x4 z = {0,0,0,0};
        z = MFMA(kf0, qf[qi][0], z);
        s[kb] = MFMA(kf1, qf[qi][1], z);
      }
      #pragma unroll
      for (int p=0;p<2;p++){
        float e0 = exp2f(s[2*p][0]),   e1 = exp2f(s[2*p][1]);
        float e2 = exp2f(s[2*p][2]),   e3 = exp2f(s[2*p][3]);
        float e4 = exp2f(s[2*p+1][0]), e5 = exp2f(s[2*p+1][1]);
        float e6 = exp2f(s[2*p+1][2]), e7 = exp2f(s[2*p+1][3]);
        union { uint4 u; bf16x8 v; } pf;
        pf.u.x = pkbf(e0,e1); pf.u.y = pkbf(e2,e3);
        pf.u.z = pkbf(e4,e5); pf.u.w = pkbf(e6,e7);
        accsum[qi] = MFMA(ones, pf.v, accsum[qi]);
        #pragma unroll
        for (int db=0;db<4;db++)
          o[qi][db] = MFMA(vf[db][p], pf.v, o[qi][db]);
      }
    }
    __syncthreads();
  }
  // epilogue: O^T layout — lane(ml=q,quad) reg r: d = db*16+quad*4+r; pack -> b64 stores
  u16* op = Opart + (size_t)ks*4096*1024;
  #pragma unroll
  for (int qi=0;qi<2;qi++){
    size_t rb = (size_t)(qbase + qi*16 + ml)*1024 + h*64;
    #pragma unroll
    for (int db=0;db<4;db++){
      uint2 w;
      w.x = pkbf(o[qi][db][0], o[qi][db][1]);
      w.y = pkbf(o[qi][db][2], o[qi][db][3]);
      *(uint2*)&op[rb + db*16 + quad*4] = w;
    }
  }
  if (quad==0){
    float* lp = Lpart + (size_t)ks*16*4096 + (size_t)h*4096 + qbase;
    lp[ml]    = accsum[0][0];
    lp[16+ml] = accsum[1][0];
  }
}

// ---------------- combine the two K-split partials, normalize, emit bf16 AO ----------------
__global__ __launch_bounds__(256) void combine_softmax(
    const u16* __restrict__ O0, const u16* __restrict__ O1,
    const float* __restrict__ L0, const float* __restrict__ L1,
    u16* __restrict__ AO)
{
  int i = (blockIdx.x*256 + threadIdx.x)*4;
  int row = i >> 10, col = i & 1023, h = col >> 6;
  float inv = 1.f/(L0[h*4096 + row] + L1[h*4096 + row]);
  ushort4 a = *(const ushort4*)(O0+i);
  ushort4 b = *(const ushort4*)(O1+i);
  ushort4 o;
  o.x = f2bf((bf2f(a.x)+bf2f(b.x))*inv);
  o.y = f2bf((bf2f(a.y)+bf2f(b.y))*inv);
  o.z = f2bf((bf2f(a.z)+bf2f(b.z))*inv);
  o.w = f2bf((bf2f(a.w)+bf2f(b.w))*inv);
  *(ushort4*)(AO+i) = o;
}

extern "C" void kernel_launch(void* const* d_in, const int* in_sizes, int n_in,
                              void* d_out, int out_size, void* d_ws, size_t ws_size,
                              hipStream_t stream)
{
  (void)in_sizes; (void)n_in; (void)out_size; (void)ws_size;
  const float* H     = (const float*)d_in[0];
  // d_in[1] = cu_seqlens (unused by reference)
  const float* cosb  = (const float*)d_in[2];
  const float* sinb  = (const float*)d_in[3];
  const float* Wqkv  = (const float*)d_in[4];
  const float* bqkv  = (const float*)d_in[5];
  const float* Wproj = (const float*)d_in[6];
  const float* bproj = (const float*)d_in[7];
  float* out = (float*)d_out;
  char* ws = (char*)d_ws;
  u16*   WqkvT  = (u16*)(ws + 0);          // [3072][1024] bf16, 6 MB; dead after QKV gemm
  float* Lpart  = (float*)(ws + 0);        // [2][16][4096] f32, 0.5 MB (reuses WqkvT)
  u16*   WprojT = (u16*)(ws + 6291456);    // [1024][1024] bf16, 2 MB
  u16*   Hb     = (u16*)(ws + 8388608);    // [4096][1024] bf16, 8 MB; dead after QKV gemm
  u16*   AO     = (u16*)(ws + 8388608);    // combine output (reuses Hb)
  u16*   QKVr   = (u16*)(ws + 16777216);   // [4096][3072] bf16, 24 MB; dead after rope
  u16*   VTb    = (u16*)(ws + 16777216);   // [16][64][4096] permuted, 8 MB (front of QKVr)
  u16*   Opart  = (u16*)(ws + 25165824);   // [2][4096][1024] bf16, 16 MB (rest of QKVr)
  u16*   Qb     = (u16*)(ws + 41943040);   // [16][4096][64], 8 MB
  u16*   Kb     = (u16*)(ws + 50331648);   // [16][4096][64], 8 MB
  u16*   Vb     = (u16*)(ws + 58720256);   // [16][4096][64], 8 MB

  hipLaunchKernelGGL(cvt_f32_bf16, dim3(4096), dim3(256), 0, stream, H, Hb, 4096*1024);
  hipLaunchKernelGGL(transpose_f32_bf16, dim3(96,32), dim3(256), 0, stream, Wqkv, WqkvT, 1024, 3072);
  hipLaunchKernelGGL(transpose_f32_bf16, dim3(32,32), dim3(256), 0, stream, Wproj, WprojT, 1024, 1024);
  hipLaunchKernelGGL((gemm_bt_bias<128,u16>), dim3(24,32), dim3(256), 0, stream, Hb, WqkvT, bqkv, QKVr, 4096, 3072, 1024);
  hipLaunchKernelGGL(rope_split, dim3(4096), dim3(256), 0, stream, QKVr, cosb, sinb, Qb, Kb, Vb);
  hipLaunchKernelGGL(vtrans_perm_bf16, dim3(128,2,16), dim3(256), 0, stream, Vb, VTb);
  hipLaunchKernelGGL(flash_attn, dim3(32,16,2), dim3(256), 0, stream, Qb, Kb, VTb, Opart, Lpart);
  hipLaunchKernelGGL(combine_softmax, dim3(4096), dim3(256), 0, stream,
                     Opart, Opart + (size_t)4096*1024, Lpart, Lpart + 16*4096, AO);
  hipLaunchKernelGGL((gemm_bt_bias<64,float>), dim3(16,32), dim3(256), 0, stream, AO, WprojT, bproj, out, 4096, 1024, 1024);
}

// Round 7
// 256.286 us; speedup vs baseline: 1.2338x; 1.0902x over previous
//
#include <hip/hip_runtime.h>
#include <type_traits>

typedef short bf16x8 __attribute__((ext_vector_type(8)));
typedef float f32x4  __attribute__((ext_vector_type(4)));
typedef unsigned short u16;

#define MFMA(a,b,c) __builtin_amdgcn_mfma_f32_16x16x32_bf16((a),(b),(c),0,0,0)

__device__ __forceinline__ float bf2f(u16 u){ unsigned x=((unsigned)u)<<16; return __builtin_bit_cast(float,x); }
__device__ __forceinline__ u16 f2bf(float f){ unsigned x=__builtin_bit_cast(unsigned,f); x += 0x7fffu + ((x>>16)&1u); return (u16)(x>>16); }

#if __has_builtin(__builtin_amdgcn_cvt_pk_bf16_f32)
typedef __bf16 hwbf2 __attribute__((ext_vector_type(2)));
__device__ __forceinline__ unsigned pkbf(float a, float b){
  hwbf2 r = __builtin_amdgcn_cvt_pk_bf16_f32(a, b);   // lo=a, hi=b, RNE
  return __builtin_bit_cast(unsigned, r);
}
#else
__device__ __forceinline__ unsigned pkbf(float a, float b){
  unsigned ua = __builtin_bit_cast(unsigned, a), ub = __builtin_bit_cast(unsigned, b);
  ua += 0x7fffu + ((ua>>16)&1u);
  ub += 0x7fffu + ((ub>>16)&1u);
  return __builtin_amdgcn_perm(ub, ua, 0x07060302u);
}
#endif

#if __has_builtin(__builtin_amdgcn_exp2f)
#define EXP2(x) __builtin_amdgcn_exp2f(x)
#else
#define EXP2(x) exp2f(x)
#endif

__device__ __forceinline__ void async_cp16(const u16* g, u16* l){
  __builtin_amdgcn_global_load_lds((const __attribute__((address_space(1))) void*)g,
                                   (__attribute__((address_space(3))) void*)l, 16, 0, 0);
}

// ---------------- fp32 -> bf16 convert ----------------
__global__ __launch_bounds__(256) void cvt_f32_bf16(const float* __restrict__ in, u16* __restrict__ out, int n){
  int i = (blockIdx.x*256 + threadIdx.x)*4;
  if (i >= n) return;
  float4 v = *(const float4*)(in + i);
  ushort4 o;
  o.x = f2bf(v.x); o.y = f2bf(v.y); o.z = f2bf(v.z); o.w = f2bf(v.w);
  *(ushort4*)(out + i) = o;
}

// ---------------- fp32 [R][C] -> bf16 [C][R] transpose ----------------
__global__ __launch_bounds__(256) void transpose_f32_bf16(const float* __restrict__ in, u16* __restrict__ out, int R, int C){
  __shared__ u16 tile[32][33];
  int bc = blockIdx.x*32, br = blockIdx.y*32;
  int tx = threadIdx.x & 31, ty = threadIdx.x >> 5;
  #pragma unroll
  for (int i=ty;i<32;i+=8) tile[i][tx] = f2bf(in[(size_t)(br+i)*C + bc + tx]);
  __syncthreads();
  #pragma unroll
  for (int i=ty;i<32;i+=8) out[(size_t)(bc+i)*R + br + tx] = tile[tx][i];
}

// ---------------- per-head bf16 transpose WITH key-permutation ----------------
// in [16][4096][64] -> out [16][64][4096]; within each 32-key group physical col
// quad*8+b*4+r holds logical key b*16+quad*4+r (S^T frag becomes PV B-operand directly).
__global__ __launch_bounds__(256) void vtrans_perm_bf16(const u16* __restrict__ in, u16* __restrict__ out){
  __shared__ u16 tile[32][33];
  const int h = blockIdx.z;
  const u16* ip = in + (size_t)h*4096*64;
  u16* op = out + (size_t)h*64*4096;
  int bt = blockIdx.x*32, bd = blockIdx.y*32;
  int tx = threadIdx.x & 31, ty = threadIdx.x >> 5;
  #pragma unroll
  for (int i=ty;i<32;i+=8) tile[i][tx] = ip[(size_t)(bt+i)*64 + bd + tx];
  __syncthreads();
  const int tlog = ((tx>>2)&1)*16 + (tx>>3)*4 + (tx&3);
  #pragma unroll
  for (int i=ty;i<32;i+=8) op[(size_t)(bd+i)*4096 + bt + tx] = tile[tlog][i];
}

// ---------------- GEMM: C[M][N] = A[M][K] @ Bt[N][K]^T + bias ----------------
template<int BN, typename OutT>
__global__ __launch_bounds__(256) void gemm_bt_bias(
    const u16* __restrict__ A, const u16* __restrict__ Bt,
    const float* __restrict__ bias, OutT* __restrict__ C,
    int M, int N, int K)
{
  __shared__ __align__(16) u16 As[128*32];
  __shared__ __align__(16) u16 Bs[BN*32];
  const int m0 = blockIdx.y*128, n0 = blockIdx.x*BN;
  const int tid = threadIdx.x;
  const int wave = tid>>6, lane = tid&63;
  const int wr = (wave>>1)*64, wc = (wave&1)*(BN/2);
  const int ml = lane&15, quad = lane>>4;
  const int lrow = lane>>2;
  const int scol = ((lane&3) ^ (lrow&3))*8;
  const int rsw  = (quad ^ (ml&3))*8;
  const u16* gA0 = A + (size_t)(m0 + wave*32      + lrow)*K + scol;
  const u16* gA1 = A + (size_t)(m0 + wave*32 + 16 + lrow)*K + scol;
  u16* lA0 = &As[wave*1024];
  u16* lA1 = &As[wave*1024 + 512];
  constexpr int BI = BN/64;
  const u16* gB[BI]; u16* lB[BI];
  #pragma unroll
  for (int t=0;t<BI;t++){
    gB[t] = Bt + (size_t)(n0 + (wave*BI+t)*16 + lrow)*K + scol;
    lB[t] = &Bs[(wave*BI+t)*512];
  }
  constexpr int NJ = BN/32;
  f32x4 acc[4][NJ] = {};
  for (int k0=0; k0<K; k0+=32) {
    async_cp16(gA0 + k0, lA0);
    async_cp16(gA1 + k0, lA1);
    #pragma unroll
    for (int t=0;t<BI;t++) async_cp16(gB[t] + k0, lB[t]);
    __syncthreads();
    bf16x8 af[4], bfr[NJ];
    #pragma unroll
    for (int i=0;i<4;i++)  af[i]  = *(const bf16x8*)&As[(wr+i*16+ml)*32 + rsw];
    #pragma unroll
    for (int j=0;j<NJ;j++) bfr[j] = *(const bf16x8*)&Bs[(wc+j*16+ml)*32 + rsw];
    #pragma unroll
    for (int i=0;i<4;i++)
      #pragma unroll
      for (int j=0;j<NJ;j++)
        acc[i][j] = MFMA(af[i], bfr[j], acc[i][j]);
    __syncthreads();
  }
  #pragma unroll
  for (int j=0;j<NJ;j++){
    int col = n0 + wc + j*16 + ml;
    float bv = bias[col];
    #pragma unroll
    for (int i=0;i<4;i++){
      int row0 = m0 + wr + i*16 + quad*4;
      #pragma unroll
      for (int r=0;r<4;r++){
        float val = acc[i][j][r] + bv;
        if constexpr (std::is_same_v<OutT, float>)
          C[(size_t)(row0+r)*N + col] = val;
        else
          C[(size_t)(row0+r)*N + col] = f2bf(val);
      }
    }
  }
}

// ---------------- RoPE + split qkv -> Q (pre-scaled 0.125*log2e), K, V row-major ----------------
__global__ __launch_bounds__(256) void rope_split(
    const u16* __restrict__ QKV, const float* __restrict__ cosb, const float* __restrict__ sinb,
    u16* __restrict__ Qo, u16* __restrict__ Ko, u16* __restrict__ Vo)
{
  const int t = blockIdx.x;
  const int d = threadIdx.x & 63;
  const int h0 = threadIdx.x >> 6;
  const float cv = cosb[t*64+d];
  const float sv = sinb[t*64+d];
  const int dp = (d<32) ? d+32 : d-32;
  const float sgn = (d<32) ? -1.f : 1.f;
  #pragma unroll
  for (int h=h0; h<16; h+=4) {
    const u16* base = QKV + (size_t)t*3072 + h*64;
    float q  = bf2f(base[d]);
    float k  = bf2f(base[1024+d]);
    float v  = bf2f(base[2048+d]);
    float qp = bf2f(base[dp]);
    float kp = bf2f(base[1024+dp]);
    float qr = q*cv + sgn*qp*sv;
    float kr = k*cv + sgn*kp*sv;
    Qo[((size_t)h*4096 + t)*64 + d] = f2bf(qr*(0.125f*1.44269504f));
    Ko[((size_t)h*4096 + t)*64 + d] = f2bf(kr);
    Vo[((size_t)h*4096 + t)*64 + d] = f2bf(v);
  }
}

// ---------------- flash attention: in-register P, K-split x4 ----------------
// grid (32 qt, 16 h, 4 ks); 4 waves x 32 q; BK=64; 1024 keys per block.
// S^T = MFMA(A=K,B=Q); kb-outer loop computes both q-subtiles per kf read.
// V^T pre-permuted so packed exp2(S^T) frags feed PV MFMA directly; sums via ones-MFMA.
__global__ __launch_bounds__(256,4) void flash_attn(
    const u16* __restrict__ Q, const u16* __restrict__ Kg, const u16* __restrict__ VT,
    u16* __restrict__ O0, u16* __restrict__ O1, u16* __restrict__ O2, u16* __restrict__ O3,
    float* __restrict__ Lpart)
{
  constexpr int SEQ=4096, QTR=1024;
  __shared__ __align__(16) u16 Ks[64*64];   // [64 keys][64 d], chunk-swizzled (c^=row&7)
  __shared__ __align__(16) u16 Vs[64*64];   // [64 d][64 keys(permuted)], chunk-swizzled
  const int qt=blockIdx.x, h=blockIdx.y, ks=blockIdx.z;
  const int tid=threadIdx.x, wave=tid>>6, lane=tid&63;
  const int ml=lane&15, quad=lane>>4;
  const int qbase = qt*128 + wave*32;
  bf16x8 qf[2][2];
  #pragma unroll
  for (int qi=0; qi<2; qi++){
    const u16* qp = Q + ((size_t)h*SEQ + qbase + qi*16 + ml)*64;
    qf[qi][0] = *(const bf16x8*)(qp + quad*8);
    qf[qi][1] = *(const bf16x8*)(qp + 32 + quad*8);
  }
  const bf16x8 ones = {0x3F80,0x3F80,0x3F80,0x3F80,0x3F80,0x3F80,0x3F80,0x3F80};
  f32x4 o[2][4] = {};
  f32x4 accsum[2] = {};
  const int lrow8 = lane>>3, lchk = lane&7;
  const int swzg = (lchk ^ lrow8)*8;
  const u16* kgl = Kg + (size_t)h*SEQ*64 + (size_t)(ks*QTR + wave*16 + lrow8)*64 + swzg;
  const u16* vgl = VT + (size_t)h*64*SEQ + (size_t)(wave*16 + lrow8)*SEQ + ks*QTR + swzg;
  u16* kl0 = &Ks[(wave*16  )*64];
  u16* kl1 = &Ks[(wave*16+8)*64];
  u16* vl0 = &Vs[(wave*16  )*64];
  u16* vl1 = &Vs[(wave*16+8)*64];
  const int swzA = (quad     ^ (ml&7))*8;
  const int swzB = ((quad^4) ^ (ml&7))*8;

  for (int k0=0;k0<QTR;k0+=64) {
    async_cp16(kgl + (size_t)k0*64,       kl0);
    async_cp16(kgl + (size_t)k0*64 + 512, kl1);
    async_cp16(vgl + k0,                  vl0);
    async_cp16(vgl + 8*SEQ + k0,          vl1);
    __syncthreads();
    // S^T for both q-subtiles, kb-outer: each kf pair read ONCE
    f32x4 s[2][4];
    #pragma unroll
    for (int kb=0;kb<4;kb++){
      bf16x8 kf0 = *(const bf16x8*)&Ks[(kb*16+ml)*64 + swzA];
      bf16x8 kf1 = *(const bf16x8*)&Ks[(kb*16+ml)*64 + swzB];
      f32x4 z0={0,0,0,0}, z1={0,0,0,0};
      z0 = MFMA(kf0, qf[0][0], z0); s[0][kb] = MFMA(kf1, qf[0][1], z0);
      z1 = MFMA(kf0, qf[1][0], z1); s[1][kb] = MFMA(kf1, qf[1][1], z1);
    }
    bf16x8 vf[4][2];
    #pragma unroll
    for (int db=0;db<4;db++){
      vf[db][0] = *(const bf16x8*)&Vs[(db*16+ml)*64 + swzA];
      vf[db][1] = *(const bf16x8*)&Vs[(db*16+ml)*64 + swzB];
    }
    #pragma unroll
    for (int qi=0; qi<2; qi++)
      #pragma unroll
      for (int p=0;p<2;p++){
        float e0 = EXP2(s[qi][2*p][0]),   e1 = EXP2(s[qi][2*p][1]);
        float e2 = EXP2(s[qi][2*p][2]),   e3 = EXP2(s[qi][2*p][3]);
        float e4 = EXP2(s[qi][2*p+1][0]), e5 = EXP2(s[qi][2*p+1][1]);
        float e6 = EXP2(s[qi][2*p+1][2]), e7 = EXP2(s[qi][2*p+1][3]);
        union { uint4 u; bf16x8 v; } pf;
        pf.u.x = pkbf(e0,e1); pf.u.y = pkbf(e2,e3);
        pf.u.z = pkbf(e4,e5); pf.u.w = pkbf(e6,e7);
        accsum[qi] = MFMA(ones, pf.v, accsum[qi]);
        #pragma unroll
        for (int db=0;db<4;db++)
          o[qi][db] = MFMA(vf[db][p], pf.v, o[qi][db]);
      }
    __syncthreads();
  }
  u16* op = (ks==0) ? O0 : (ks==1) ? O1 : (ks==2) ? O2 : O3;
  #pragma unroll
  for (int qi=0;qi<2;qi++){
    size_t rb = (size_t)(qbase + qi*16 + ml)*1024 + h*64;
    #pragma unroll
    for (int db=0;db<4;db++){
      uint2 w;
      w.x = pkbf(o[qi][db][0], o[qi][db][1]);
      w.y = pkbf(o[qi][db][2], o[qi][db][3]);
      *(uint2*)&op[rb + db*16 + quad*4] = w;
    }
  }
  if (quad==0){
    float* lp = Lpart + (size_t)ks*65536 + (size_t)h*4096 + qbase;
    lp[ml]    = accsum[0][0];
    lp[16+ml] = accsum[1][0];
  }
}

// ---------------- combine the four K-split partials, normalize, emit bf16 AO ----------------
__global__ __launch_bounds__(256) void combine_softmax4(
    const u16* __restrict__ O0, const u16* __restrict__ O1,
    const u16* __restrict__ O2, const u16* __restrict__ O3,
    const float* __restrict__ L, u16* __restrict__ AO)
{
  int i = (blockIdx.x*256 + threadIdx.x)*4;
  int row = i >> 10, col = i & 1023, h = col >> 6;
  int li = h*4096 + row;
  float inv = 1.f/(L[li] + L[li+65536] + L[li+2*65536] + L[li+3*65536]);
  ushort4 a = *(const ushort4*)(O0+i);
  ushort4 b = *(const ushort4*)(O1+i);
  ushort4 c = *(const ushort4*)(O2+i);
  ushort4 d = *(const ushort4*)(O3+i);
  ushort4 o;
  o.x = f2bf((bf2f(a.x)+bf2f(b.x)+bf2f(c.x)+bf2f(d.x))*inv);
  o.y = f2bf((bf2f(a.y)+bf2f(b.y)+bf2f(c.y)+bf2f(d.y))*inv);
  o.z = f2bf((bf2f(a.z)+bf2f(b.z)+bf2f(c.z)+bf2f(d.z))*inv);
  o.w = f2bf((bf2f(a.w)+bf2f(b.w)+bf2f(c.w)+bf2f(d.w))*inv);
  *(ushort4*)(AO+i) = o;
}

extern "C" void kernel_launch(void* const* d_in, const int* in_sizes, int n_in,
                              void* d_out, int out_size, void* d_ws, size_t ws_size,
                              hipStream_t stream)
{
  (void)in_sizes; (void)n_in; (void)out_size; (void)ws_size;
  const float* H     = (const float*)d_in[0];
  // d_in[1] = cu_seqlens (unused by reference)
  const float* cosb  = (const float*)d_in[2];
  const float* sinb  = (const float*)d_in[3];
  const float* Wqkv  = (const float*)d_in[4];
  const float* bqkv  = (const float*)d_in[5];
  const float* Wproj = (const float*)d_in[6];
  const float* bproj = (const float*)d_in[7];
  float* out = (float*)d_out;
  char* ws = (char*)d_ws;
  // layout (64 MiB budget), aliasing dead regions:
  float* Lpart  = (float*)(ws + 0);        // [4][16][4096] f32, 1 MB
  u16*   WprojT = (u16*)(ws + 2097152);    // [1024][1024] bf16, 2 MB
  u16*   Hb     = (u16*)(ws + 4194304);    // [4096][1024] bf16, 8 MB; dead after QKV gemm
  u16*   Opart2 = (u16*)(ws + 4194304);    //   (reuses Hb)
  u16*   QKVr   = (u16*)(ws + 12582912);   // [4096][3072] bf16, 24 MB; dead after rope
  u16*   VTb    = (u16*)(ws + 12582912);   //   [16][64][4096] permuted, 8 MB (front of QKVr)
  u16*   Opart0 = (u16*)(ws + 20971520);   //   8 MB (QKVr tail, dead after rope)
  u16*   Opart1 = (u16*)(ws + 29360128);   //   8 MB
  u16*   WqkvT  = (u16*)(ws + 37748736);   // [3072][1024] bf16, 6 MB; dead after QKV gemm
  u16*   Qb     = (u16*)(ws + 37748736);   //   [16][4096][64], 8 MB (reuses WqkvT)
  u16*   AO     = (u16*)(ws + 37748736);   //   combine out (Qb dead after flash)
  u16*   Kb     = (u16*)(ws + 46137344);   // [16][4096][64], 8 MB
  u16*   Vb     = (u16*)(ws + 54525952);   // [16][4096][64], 8 MB; dead after vtrans
  u16*   Opart3 = (u16*)(ws + 54525952);   //   (reuses Vb)

  hipLaunchKernelGGL(cvt_f32_bf16, dim3(4096), dim3(256), 0, stream, H, Hb, 4096*1024);
  hipLaunchKernelGGL(transpose_f32_bf16, dim3(96,32), dim3(256), 0, stream, Wqkv, WqkvT, 1024, 3072);
  hipLaunchKernelGGL(transpose_f32_bf16, dim3(32,32), dim3(256), 0, stream, Wproj, WprojT, 1024, 1024);
  hipLaunchKernelGGL((gemm_bt_bias<128,u16>), dim3(24,32), dim3(256), 0, stream, Hb, WqkvT, bqkv, QKVr, 4096, 3072, 1024);
  hipLaunchKernelGGL(rope_split, dim3(4096), dim3(256), 0, stream, QKVr, cosb, sinb, Qb, Kb, Vb);
  hipLaunchKernelGGL(vtrans_perm_bf16, dim3(128,2,16), dim3(256), 0, stream, Vb, VTb);
  hipLaunchKernelGGL(flash_attn, dim3(32,16,4), dim3(256), 0, stream, Qb, Kb, VTb,
                     Opart0, Opart1, Opart2, Opart3, Lpart);
  hipLaunchKernelGGL(combine_softmax4, dim3(4096), dim3(256), 0, stream,
                     Opart0, Opart1, Opart2, Opart3, Lpart, AO);
  hipLaunchKernelGGL((gemm_bt_bias<64,float>), dim3(16,32), dim3(256), 0, stream, AO, WprojT, bproj, out, 4096, 1024, 1024);
}